// Round 6
// baseline (974.681 us; speedup 1.0000x reference)
//
#include <hip/hip_runtime.h>
#include <hip/hip_bf16.h>

typedef __attribute__((ext_vector_type(8))) short bf16x8;
typedef __attribute__((ext_vector_type(4))) float f32x4;

#define NNODES 8192
#define NEDGES 65536
#define FIN 256
#define FOUT 64
#define EDIM 32

// workspace byte offsets
#define WS_HN    0x000000u   // 2 MB
#define WS_HS    0x200000u   // 2 MB
#define WS_MSG   0x400000u   // 16 MB (slot-order msg = s[e]*hn[src[e]])
#define WS_DEG   0x1400000u  // 32 KB
#define WS_OFF   0x1408000u  // 32 KB
#define WS_RANK  0x1410000u  // 256 KB
#define WS_PERM  0x1450000u  // 256 KB (slot -> edge id)
#define WS_GSRC  0x1490000u  // 256 KB (slot -> src node)
#define WS_WBF   0x14D0000u  // 256 KB bf16 W_edge
#define WS_WPREB 0x1510000u  // 32 KB bf16 W_preagg
#define WS_WST   0x1520000u  // 16 KB
#define WS_WNT   0x1524000u  // 16 KB

__device__ __forceinline__ unsigned short f2bf(float f) {
    unsigned u = __builtin_bit_cast(unsigned, f);
    u = (u + 0x7fffu + ((u >> 16) & 1u)) >> 16;   // RNE
    return (unsigned short)u;
}

__device__ __forceinline__ bf16x8 pack8(float4 v0, float4 v1) {
    bf16x8 r;
    r[0] = (short)f2bf(v0.x); r[1] = (short)f2bf(v0.y);
    r[2] = (short)f2bf(v0.z); r[3] = (short)f2bf(v0.w);
    r[4] = (short)f2bf(v1.x); r[5] = (short)f2bf(v1.y);
    r[6] = (short)f2bf(v1.z); r[7] = (short)f2bf(v1.w);
    return r;
}

// ---------------- K1: prep (weight transforms) || count (deg histogram + rank) ------
__global__ __launch_bounds__(256) void prep_count_kernel(
    const float* __restrict__ W_edge,
    const float* __restrict__ W_preagg,
    const float* __restrict__ W_self,
    const float* __restrict__ W_neigh,
    const int* __restrict__ dst,
    unsigned short* __restrict__ wbf,
    unsigned short* __restrict__ wpreB,
    float* __restrict__ wsT,
    float* __restrict__ wnT,
    int* __restrict__ deg,
    int* __restrict__ rank) {
    int b = blockIdx.x, t = threadIdx.x;
    if (b < 512) {
        int i = b * 256 + t;
        if (i < FOUT * FOUT * EDIM) wbf[i] = f2bf(W_edge[i]);     // 131072
        if (i < FOUT * FIN) wpreB[i] = f2bf(W_preagg[i]);         // 16384, row-major
        if (i < FOUT * FOUT) {
            int o = i >> 6, k = i & 63;
            wsT[k * FOUT + o] = W_self[i];
            wnT[k * FOUT + o] = W_neigh[i];
        }
    } else {
        int e = (b - 512) * 256 + t;
        rank[e] = atomicAdd(deg + dst[e], 1);
    }
}

// ---------------- K2: preagg as MFMA GEMM (no LDS) || scan ----------------
// wave = 16 rows x 64 outs; 4 waves/block; blocks [0,256) cover 16384 rows; block 256 = scan
__global__ __launch_bounds__(256) void preagg_scan_kernel(
    const float* __restrict__ h_neigh,
    const float* __restrict__ h_self,
    const unsigned short* __restrict__ wpreB,
    const int* __restrict__ deg,
    float* __restrict__ hn,
    float* __restrict__ hs,
    int* __restrict__ off) {
    __shared__ int wsum[4];
    int b = blockIdx.x, t = threadIdx.x;
    if (b == 256) {                      // scan, single block
        int lane = t & 63, w = t >> 6;
        int base = t * 32;
        int loc[32];
        int s = 0;
        #pragma unroll
        for (int i = 0; i < 32; ++i) { loc[i] = s; s += deg[base + i]; }
        int v = s;
        #pragma unroll
        for (int d = 1; d < 64; d <<= 1) {
            int u = __shfl_up(v, d);
            if (lane >= d) v += u;
        }
        if (lane == 63) wsum[w] = v;
        int threadExcl = v - s;
        __syncthreads();
        int wexcl = 0;
        for (int i = 0; i < w; ++i) wexcl += wsum[i];
        int tbase = wexcl + threadExcl;
        #pragma unroll
        for (int i = 0; i < 32; ++i) off[base + i] = tbase + loc[i];
        return;
    }
    int w = t >> 6, lane = t & 63;
    int rowm = lane & 15, kc = lane >> 4;
    int g0 = (b * 4 + w) * 16;           // global row group [g0, g0+16)
    const float* hsrc;
    float* outp;
    int r0;
    if (g0 < NNODES) { hsrc = h_neigh; outp = hn; r0 = g0; }
    else             { hsrc = h_self;  outp = hs; r0 = g0 - NNODES; }
    const float* arow = hsrc + (size_t)(r0 + rowm) * FIN;

    f32x4 acc[4];
    #pragma unroll
    for (int ot = 0; ot < 4; ++ot) acc[ot] = f32x4{0.f, 0.f, 0.f, 0.f};

    #pragma unroll
    for (int ks = 0; ks < 8; ++ks) {
        const float* p = arow + ks * 32 + kc * 8;
        float4 v0 = reinterpret_cast<const float4*>(p)[0];
        float4 v1 = reinterpret_cast<const float4*>(p)[1];
        bf16x8 af = pack8(v0, v1);
        #pragma unroll
        for (int ot = 0; ot < 4; ++ot) {
            // B[k][o] = W_preagg[o][k]; lane holds W[o = ot*16+rowm][k = ks*32+kc*8 ..+8)
            bf16x8 bfv = *reinterpret_cast<const bf16x8*>(
                wpreB + ((ot * 16 + rowm) * FIN + ks * 32 + kc * 8));
            acc[ot] = __builtin_amdgcn_mfma_f32_16x16x32_bf16(af, bfv, acc[ot], 0, 0, 0);
        }
    }
    // C/D: col(o_local)=rowm, row=kc*4+r
    #pragma unroll
    for (int ot = 0; ot < 4; ++ot)
        #pragma unroll
        for (int r = 0; r < 4; ++r)
            outp[(size_t)(r0 + kc * 4 + r) * FOUT + ot * 16 + rowm] =
                fmaxf(acc[ot][r], 0.f);
}

// ---------------- K3: fill slot tables ----------------
__global__ void fill_kernel(const int* __restrict__ src,
                            const int* __restrict__ dst,
                            const int* __restrict__ off,
                            const int* __restrict__ rank,
                            int* __restrict__ perm,
                            int* __restrict__ gsrc) {
    int e = blockIdx.x * 256 + threadIdx.x;
    int slot = off[dst[e]] + rank[e];
    perm[slot] = e;
    gsrc[slot] = src[e];
}

// ---------------- K4: edge GEMM in slot order, fused hn-mul, contiguous msg store ---
// block = 256 thr = 4 waves = 4 col-quarters (cw); block owns 64 slots; grid 1024
// wave: gathers A rows ef[perm[slot]], B direct from L2, depth-8 pipeline
__global__ __launch_bounds__(256, 4) void edge_kernel(
    const float* __restrict__ ef,
    const unsigned short* __restrict__ wbf,
    const float* __restrict__ b_edge,
    const float* __restrict__ hn,
    const int* __restrict__ perm,
    const int* __restrict__ gsrc,
    float* __restrict__ msg) {
    int t = threadIdx.x;
    int cw = t >> 6, lane = t & 63;
    int rowm = lane & 15, kc = lane >> 4, k0 = kc * 8;
    int e0 = blockIdx.x * 64;
    int colbase = cw * 16 + rowm;

    // A fragments: lane holds ef[perm[e0 + tt*16 + rowm]][k0 .. k0+8)
    bf16x8 a[4];
    #pragma unroll
    for (int tt = 0; tt < 4; ++tt) {
        int eidx = perm[e0 + tt * 16 + rowm];
        const float* p = ef + (size_t)eidx * EDIM + k0;
        float4 v0 = reinterpret_cast<const float4*>(p)[0];
        float4 v1 = reinterpret_cast<const float4*>(p)[1];
        a[tt] = pack8(v0, v1);
    }

    f32x4 sacc[4];
    #pragma unroll
    for (int tt = 0; tt < 4; ++tt) sacc[tt] = f32x4{0.f, 0.f, 0.f, 0.f};
    const f32x4 z4 = {0.f, 0.f, 0.f, 0.f};
    const char* wb = reinterpret_cast<const char*>(wbf);

    // depth-8 software pipeline over g in [0,64): col = g*64 + colbase
    bf16x8 bb[8];
    float bs[8];
    #pragma unroll
    for (int p = 0; p < 8; ++p) {
        bb[p] = *reinterpret_cast<const bf16x8*>(
            wb + (size_t)((p * 64 + colbase) * 64 + kc * 16));
        bs[p] = b_edge[p * 64 + colbase];
    }
    #pragma unroll
    for (int gb = 0; gb < 64; gb += 8) {
        #pragma unroll
        for (int p = 0; p < 8; ++p) {
            bf16x8 bcur = bb[p];
            float bias = bs[p];
            int gn = gb + 8 + p;
            if (gn < 64) {               // compile-time (fully unrolled)
                bb[p] = *reinterpret_cast<const bf16x8*>(
                    wb + (size_t)((gn * 64 + colbase) * 64 + kc * 16));
                bs[p] = b_edge[gn * 64 + colbase];
            }
            f32x4 cin = {bias, bias, bias, bias};
            #pragma unroll
            for (int tt = 0; tt < 4; ++tt) {
                f32x4 d = __builtin_amdgcn_mfma_f32_16x16x32_bf16(a[tt], bcur, cin, 0, 0, 0);
                sacc[tt] += __builtin_elementwise_max(d, z4);   // relu + i-fold
            }
        }
    }

    // epilogue: msg[slot][j] = s * hn[gsrc[slot]][j]; contiguous 64B per quarter-wave
    #pragma unroll
    for (int tt = 0; tt < 4; ++tt) {
        #pragma unroll
        for (int r = 0; r < 4; ++r) {
            int slot = e0 + tt * 16 + kc * 4 + r;
            int se = gsrc[slot];                       // broadcast per quarter-wave
            float hv = hn[(size_t)se * FOUT + colbase];
            msg[(size_t)slot * FOUT + colbase] = sacc[tt][r] * hv;
        }
    }
}

// ---------------- K5: final — streaming mean over contiguous slots + two FCs --------
__global__ __launch_bounds__(256) void final_kernel(
    const float* __restrict__ hs,
    const float* __restrict__ msg,
    const int* __restrict__ deg,
    const int* __restrict__ off,
    const float* __restrict__ wsT,
    const float* __restrict__ wnT,
    float* __restrict__ out) {
    __shared__ float sm[4][2][FOUT];
    int t = threadIdx.x, w = t >> 6, lane = t & 63;
    int n = blockIdx.x * 4 + w;
    int o0 = off[n], d = deg[n];
    const float* mp = msg + (size_t)o0 * FOUT + lane;
    float acc = 0.f;
    int i = 0;
    for (; i + 4 <= d; i += 4) {
        float m0 = mp[(size_t)(i + 0) * FOUT];
        float m1 = mp[(size_t)(i + 1) * FOUT];
        float m2 = mp[(size_t)(i + 2) * FOUT];
        float m3 = mp[(size_t)(i + 3) * FOUT];
        acc += (m0 + m1) + (m2 + m3);
    }
    for (; i < d; ++i) acc += mp[(size_t)i * FOUT];
    float neigh = acc / fmaxf((float)d, 1.f);
    sm[w][0][lane] = neigh;
    sm[w][1][lane] = hs[(size_t)n * FOUT + lane];
    __syncthreads();
    float a1 = 0.f, a2 = 0.f;
    #pragma unroll 8
    for (int k = 0; k < FOUT; ++k) {
        a1 = fmaf(sm[w][1][k], wsT[k * FOUT + lane], a1);
        a2 = fmaf(sm[w][0][k], wnT[k * FOUT + lane], a2);
    }
    out[(size_t)n * FOUT + lane] = fmaxf(fmaxf(a1, 0.f) + fmaxf(a2, 0.f), 0.f);
}

extern "C" void kernel_launch(void* const* d_in, const int* in_sizes, int n_in,
                              void* d_out, int out_size, void* d_ws, size_t ws_size,
                              hipStream_t stream) {
    const float* h_neigh  = (const float*)d_in[0];
    const float* h_self   = (const float*)d_in[1];
    const float* ef       = (const float*)d_in[2];
    const float* W_preagg = (const float*)d_in[3];
    const float* W_self   = (const float*)d_in[4];
    const float* W_neigh  = (const float*)d_in[5];
    const float* W_edge   = (const float*)d_in[6];
    const float* b_edge   = (const float*)d_in[7];
    const int*   src      = (const int*)d_in[8];
    const int*   dst      = (const int*)d_in[9];
    float* out = (float*)d_out;
    char* ws = (char*)d_ws;

    float* hn    = (float*)(ws + WS_HN);
    float* hs    = (float*)(ws + WS_HS);
    float* msg   = (float*)(ws + WS_MSG);
    int*   deg   = (int*)(ws + WS_DEG);
    int*   off   = (int*)(ws + WS_OFF);
    int*   rank  = (int*)(ws + WS_RANK);
    int*   perm  = (int*)(ws + WS_PERM);
    int*   gsrc  = (int*)(ws + WS_GSRC);
    unsigned short* wbf   = (unsigned short*)(ws + WS_WBF);
    unsigned short* wpreB = (unsigned short*)(ws + WS_WPREB);
    float* wsT   = (float*)(ws + WS_WST);
    float* wnT   = (float*)(ws + WS_WNT);

    // zero deg every call (count accumulates via atomics)
    hipMemsetAsync(ws + WS_DEG, 0, 0x8000, stream);

    prep_count_kernel<<<768, 256, 0, stream>>>(W_edge, W_preagg, W_self, W_neigh,
                                               dst, wbf, wpreB, wsT, wnT, deg, rank);
    preagg_scan_kernel<<<257, 256, 0, stream>>>(h_neigh, h_self, wpreB, deg,
                                                hn, hs, off);
    fill_kernel<<<NEDGES / 256, 256, 0, stream>>>(src, dst, off, rank, perm, gsrc);
    edge_kernel<<<1024, 256, 0, stream>>>(ef, wbf, b_edge, hn, perm, gsrc, msg);
    final_kernel<<<NNODES / 4, 256, 0, stream>>>(hs, msg, deg, off, wsT, wnT, out);
}

// Round 8
// 274.582 us; speedup vs baseline: 3.5497x; 3.5497x over previous
//
#include <hip/hip_runtime.h>
#include <hip/hip_bf16.h>

typedef __attribute__((ext_vector_type(8))) short bf16x8;
typedef __attribute__((ext_vector_type(4))) float f32x4;

#define NNODES 8192
#define NEDGES 65536
#define FIN 256
#define FOUT 64
#define EDIM 32

// workspace byte offsets
#define WS_HN    0x000000u   // 2 MB
#define WS_HS    0x200000u   // 2 MB
#define WS_MSG   0x400000u   // 16 MB (slot-order msg = s[e]*hn[src[e]])
#define WS_DEG   0x1400000u  // 32 KB
#define WS_OFF   0x1408000u  // 32 KB
#define WS_RANK  0x1410000u  // 256 KB
#define WS_PERM  0x1450000u  // 256 KB (slot -> edge id)
#define WS_GSRC  0x1490000u  // 256 KB (slot -> src node)
#define WS_WBH   0x14D0000u  // 256 KB bf16 W_edge hi
#define WS_WBL   0x1510000u  // 256 KB bf16 W_edge lo (residual)
#define WS_WPH   0x1550000u  // 32 KB bf16 W_preagg hi
#define WS_WPL   0x1558000u  // 32 KB bf16 W_preagg lo
#define WS_WST   0x1560000u  // 16 KB fp32 W_self^T
#define WS_WNT   0x1564000u  // 16 KB fp32 W_neigh^T

__device__ __forceinline__ unsigned short f2bf(float f) {
    unsigned u = __builtin_bit_cast(unsigned, f);
    u = (u + 0x7fffu + ((u >> 16) & 1u)) >> 16;   // RNE
    return (unsigned short)u;
}
__device__ __forceinline__ float bf2f(unsigned short h) {
    unsigned u = ((unsigned)h) << 16;
    return __builtin_bit_cast(float, u);
}
// split fp32 -> hi bf16 + lo bf16 (residual); x ~= hi + lo to ~2^-17 rel
__device__ __forceinline__ void split8(float4 v0, float4 v1, bf16x8& hi, bf16x8& lo) {
    float x[8] = {v0.x, v0.y, v0.z, v0.w, v1.x, v1.y, v1.z, v1.w};
    #pragma unroll
    for (int j = 0; j < 8; ++j) {
        unsigned short h = f2bf(x[j]);
        hi[j] = (short)h;
        lo[j] = (short)f2bf(x[j] - bf2f(h));
    }
}

// ---------------- K1: prep (weight transforms, hi+lo split) || count ----------------
__global__ __launch_bounds__(256) void prep_count_kernel(
    const float* __restrict__ W_edge,
    const float* __restrict__ W_preagg,
    const float* __restrict__ W_self,
    const float* __restrict__ W_neigh,
    const int* __restrict__ dst,
    unsigned short* __restrict__ wbh,
    unsigned short* __restrict__ wbl,
    unsigned short* __restrict__ wph,
    unsigned short* __restrict__ wpl,
    float* __restrict__ wsT,
    float* __restrict__ wnT,
    int* __restrict__ deg,
    int* __restrict__ rank) {
    int b = blockIdx.x, t = threadIdx.x;
    if (b < 512) {
        int i = b * 256 + t;
        if (i < FOUT * FOUT * EDIM) {                 // 131072
            float wv = W_edge[i];
            unsigned short h = f2bf(wv);
            wbh[i] = h;
            wbl[i] = f2bf(wv - bf2f(h));
        }
        if (i < FOUT * FIN) {                         // 16384, row-major [64][256]
            float wv = W_preagg[i];
            unsigned short h = f2bf(wv);
            wph[i] = h;
            wpl[i] = f2bf(wv - bf2f(h));
        }
        if (i < FOUT * FOUT) {                        // 4096
            int o = i >> 6, k = i & 63;
            wsT[k * FOUT + o] = W_self[i];
            wnT[k * FOUT + o] = W_neigh[i];
        }
    } else {
        int e = (b - 512) * 256 + t;
        rank[e] = atomicAdd(deg + dst[e], 1);
    }
}

// ---------------- K2: preagg as split-bf16 MFMA GEMM (no LDS) || scan ----------------
// wave = 16 rows x 64 outs; 4 waves/block; blocks [0,256) cover 16384 rows; blk 256 = scan
__global__ __launch_bounds__(256) void preagg_scan_kernel(
    const float* __restrict__ h_neigh,
    const float* __restrict__ h_self,
    const unsigned short* __restrict__ wph,
    const unsigned short* __restrict__ wpl,
    const int* __restrict__ deg,
    float* __restrict__ hn,
    float* __restrict__ hs,
    int* __restrict__ off) {
    __shared__ int wsum[4];
    int b = blockIdx.x, t = threadIdx.x;
    if (b == 256) {                      // scan, single block
        int lane = t & 63, w = t >> 6;
        int base = t * 32;
        int loc[32];
        int s = 0;
        #pragma unroll
        for (int i = 0; i < 32; ++i) { loc[i] = s; s += deg[base + i]; }
        int v = s;
        #pragma unroll
        for (int d = 1; d < 64; d <<= 1) {
            int u = __shfl_up(v, d);
            if (lane >= d) v += u;
        }
        if (lane == 63) wsum[w] = v;
        int threadExcl = v - s;
        __syncthreads();
        int wexcl = 0;
        for (int i = 0; i < w; ++i) wexcl += wsum[i];
        int tbase = wexcl + threadExcl;
        #pragma unroll
        for (int i = 0; i < 32; ++i) off[base + i] = tbase + loc[i];
        return;
    }
    int w = t >> 6, lane = t & 63;
    int rowm = lane & 15, kc = lane >> 4;
    int g0 = (b * 4 + w) * 16;           // global row group [g0, g0+16)
    const float* hsrc;
    float* outp;
    int r0;
    if (g0 < NNODES) { hsrc = h_neigh; outp = hn; r0 = g0; }
    else             { hsrc = h_self;  outp = hs; r0 = g0 - NNODES; }
    const float* arow = hsrc + (size_t)(r0 + rowm) * FIN;

    f32x4 acc[4];
    #pragma unroll
    for (int ot = 0; ot < 4; ++ot) acc[ot] = f32x4{0.f, 0.f, 0.f, 0.f};

    #pragma unroll
    for (int ks = 0; ks < 8; ++ks) {
        const float* p = arow + ks * 32 + kc * 8;
        float4 v0 = reinterpret_cast<const float4*>(p)[0];
        float4 v1 = reinterpret_cast<const float4*>(p)[1];
        bf16x8 ahi, alo;
        split8(v0, v1, ahi, alo);
        #pragma unroll
        for (int ot = 0; ot < 4; ++ot) {
            int woff = (ot * 16 + rowm) * FIN + ks * 32 + kc * 8;
            bf16x8 bh = *reinterpret_cast<const bf16x8*>(wph + woff);
            bf16x8 bl = *reinterpret_cast<const bf16x8*>(wpl + woff);
            acc[ot] = __builtin_amdgcn_mfma_f32_16x16x32_bf16(ahi, bh, acc[ot], 0, 0, 0);
            acc[ot] = __builtin_amdgcn_mfma_f32_16x16x32_bf16(alo, bh, acc[ot], 0, 0, 0);
            acc[ot] = __builtin_amdgcn_mfma_f32_16x16x32_bf16(ahi, bl, acc[ot], 0, 0, 0);
        }
    }
    #pragma unroll
    for (int ot = 0; ot < 4; ++ot)
        #pragma unroll
        for (int r = 0; r < 4; ++r)
            outp[(size_t)(r0 + kc * 4 + r) * FOUT + ot * 16 + rowm] =
                fmaxf(acc[ot][r], 0.f);
}

// ---------------- K3: fill slot tables ----------------
__global__ void fill_kernel(const int* __restrict__ src,
                            const int* __restrict__ dst,
                            const int* __restrict__ off,
                            const int* __restrict__ rank,
                            int* __restrict__ perm,
                            int* __restrict__ gsrc) {
    int e = blockIdx.x * 256 + threadIdx.x;
    int slot = off[dst[e]] + rank[e];
    perm[slot] = e;
    gsrc[slot] = src[e];
}

// ---------------- K4: edge GEMM (split-bf16, 3-MFMA chain), slot order, fused hn-mul
// block = 256 thr = 4 waves = 4 col-quarters (cw); block owns 64 slots; grid 1024.
// B (hi+lo) direct from L2, depth-4 pipeline; NO min-waves clause (spill lesson, r6).
__global__ __launch_bounds__(256) void edge_kernel(
    const float* __restrict__ ef,
    const unsigned short* __restrict__ wbh,
    const unsigned short* __restrict__ wbl,
    const float* __restrict__ b_edge,
    const float* __restrict__ hn,
    const int* __restrict__ perm,
    const int* __restrict__ gsrc,
    float* __restrict__ msg) {
    int t = threadIdx.x;
    int cw = t >> 6, lane = t & 63;
    int rowm = lane & 15, kc = lane >> 4, k0 = kc * 8;
    int e0 = blockIdx.x * 64;
    int colbase = cw * 16 + rowm;

    // A fragments (hi+lo): lane holds ef[perm[e0 + tt*16 + rowm]][k0 .. k0+8)
    bf16x8 ahi[4], alo[4];
    #pragma unroll
    for (int tt = 0; tt < 4; ++tt) {
        int eidx = perm[e0 + tt * 16 + rowm];
        const float* p = ef + (size_t)eidx * EDIM + k0;
        float4 v0 = reinterpret_cast<const float4*>(p)[0];
        float4 v1 = reinterpret_cast<const float4*>(p)[1];
        split8(v0, v1, ahi[tt], alo[tt]);
    }

    f32x4 sacc[4];
    #pragma unroll
    for (int tt = 0; tt < 4; ++tt) sacc[tt] = f32x4{0.f, 0.f, 0.f, 0.f};
    const f32x4 z4 = {0.f, 0.f, 0.f, 0.f};
    const char* wbh_c = reinterpret_cast<const char*>(wbh);
    const char* wbl_c = reinterpret_cast<const char*>(wbl);

    // depth-4 software pipeline over g in [0,64): col = g*64 + colbase
    bf16x8 bbh[4], bbl[4];
    float bs[4];
    #pragma unroll
    for (int p = 0; p < 4; ++p) {
        size_t boff = (size_t)((p * 64 + colbase) * 64 + kc * 16);
        bbh[p] = *reinterpret_cast<const bf16x8*>(wbh_c + boff);
        bbl[p] = *reinterpret_cast<const bf16x8*>(wbl_c + boff);
        bs[p] = b_edge[p * 64 + colbase];
    }
    #pragma unroll
    for (int gb = 0; gb < 64; gb += 4) {
        #pragma unroll
        for (int p = 0; p < 4; ++p) {
            bf16x8 bh = bbh[p], bl = bbl[p];
            float bias = bs[p];
            int gn = gb + 4 + p;
            if (gn < 64) {               // compile-time (fully unrolled)
                size_t boff = (size_t)((gn * 64 + colbase) * 64 + kc * 16);
                bbh[p] = *reinterpret_cast<const bf16x8*>(wbh_c + boff);
                bbl[p] = *reinterpret_cast<const bf16x8*>(wbl_c + boff);
                bs[p] = b_edge[gn * 64 + colbase];
            }
            f32x4 cin = {bias, bias, bias, bias};
            #pragma unroll
            for (int tt = 0; tt < 4; ++tt) {
                // ew = Ahi*Bhi + Alo*Bhi + Ahi*Blo (+ O(2^-18)) + bias
                f32x4 d = __builtin_amdgcn_mfma_f32_16x16x32_bf16(ahi[tt], bh, cin, 0, 0, 0);
                d = __builtin_amdgcn_mfma_f32_16x16x32_bf16(alo[tt], bh, d, 0, 0, 0);
                d = __builtin_amdgcn_mfma_f32_16x16x32_bf16(ahi[tt], bl, d, 0, 0, 0);
                sacc[tt] += __builtin_elementwise_max(d, z4);   // relu + i-fold
            }
        }
    }

    // epilogue: msg[slot][j] = s * hn[gsrc[slot]][j]; 64B contiguous per 1/4-wave
    #pragma unroll
    for (int tt = 0; tt < 4; ++tt) {
        #pragma unroll
        for (int r = 0; r < 4; ++r) {
            int slot = e0 + tt * 16 + kc * 4 + r;
            int se = gsrc[slot];
            float hv = hn[(size_t)se * FOUT + colbase];
            msg[(size_t)slot * FOUT + colbase] = sacc[tt][r] * hv;
        }
    }
}

// ---------------- K5: final — streaming mean over contiguous slots + two FCs --------
__global__ __launch_bounds__(256) void final_kernel(
    const float* __restrict__ hs,
    const float* __restrict__ msg,
    const int* __restrict__ deg,
    const int* __restrict__ off,
    const float* __restrict__ wsT,
    const float* __restrict__ wnT,
    float* __restrict__ out) {
    __shared__ float sm[4][2][FOUT];
    int t = threadIdx.x, w = t >> 6, lane = t & 63;
    int n = blockIdx.x * 4 + w;
    int o0 = off[n], d = deg[n];
    const float* mp = msg + (size_t)o0 * FOUT + lane;
    float acc = 0.f;
    int i = 0;
    for (; i + 4 <= d; i += 4) {
        float m0 = mp[(size_t)(i + 0) * FOUT];
        float m1 = mp[(size_t)(i + 1) * FOUT];
        float m2 = mp[(size_t)(i + 2) * FOUT];
        float m3 = mp[(size_t)(i + 3) * FOUT];
        acc += (m0 + m1) + (m2 + m3);
    }
    for (; i < d; ++i) acc += mp[(size_t)i * FOUT];
    float neigh = acc / fmaxf((float)d, 1.f);
    sm[w][0][lane] = neigh;
    sm[w][1][lane] = hs[(size_t)n * FOUT + lane];
    __syncthreads();
    float a1 = 0.f, a2 = 0.f;
    #pragma unroll 8
    for (int k = 0; k < FOUT; ++k) {
        a1 = fmaf(sm[w][1][k], wsT[k * FOUT + lane], a1);
        a2 = fmaf(sm[w][0][k], wnT[k * FOUT + lane], a2);
    }
    out[(size_t)n * FOUT + lane] = fmaxf(fmaxf(a1, 0.f) + fmaxf(a2, 0.f), 0.f);
}

extern "C" void kernel_launch(void* const* d_in, const int* in_sizes, int n_in,
                              void* d_out, int out_size, void* d_ws, size_t ws_size,
                              hipStream_t stream) {
    const float* h_neigh  = (const float*)d_in[0];
    const float* h_self   = (const float*)d_in[1];
    const float* ef       = (const float*)d_in[2];
    const float* W_preagg = (const float*)d_in[3];
    const float* W_self   = (const float*)d_in[4];
    const float* W_neigh  = (const float*)d_in[5];
    const float* W_edge   = (const float*)d_in[6];
    const float* b_edge   = (const float*)d_in[7];
    const int*   src      = (const int*)d_in[8];
    const int*   dst      = (const int*)d_in[9];
    float* out = (float*)d_out;
    char* ws = (char*)d_ws;

    float* hn    = (float*)(ws + WS_HN);
    float* hs    = (float*)(ws + WS_HS);
    float* msg   = (float*)(ws + WS_MSG);
    int*   deg   = (int*)(ws + WS_DEG);
    int*   off   = (int*)(ws + WS_OFF);
    int*   rank  = (int*)(ws + WS_RANK);
    int*   perm  = (int*)(ws + WS_PERM);
    int*   gsrc  = (int*)(ws + WS_GSRC);
    unsigned short* wbh = (unsigned short*)(ws + WS_WBH);
    unsigned short* wbl = (unsigned short*)(ws + WS_WBL);
    unsigned short* wph = (unsigned short*)(ws + WS_WPH);
    unsigned short* wpl = (unsigned short*)(ws + WS_WPL);
    float* wsT   = (float*)(ws + WS_WST);
    float* wnT   = (float*)(ws + WS_WNT);

    // zero deg every call (count accumulates via atomics)
    hipMemsetAsync(ws + WS_DEG, 0, 0x8000, stream);

    prep_count_kernel<<<768, 256, 0, stream>>>(W_edge, W_preagg, W_self, W_neigh,
                                               dst, wbh, wbl, wph, wpl, wsT, wnT,
                                               deg, rank);
    preagg_scan_kernel<<<257, 256, 0, stream>>>(h_neigh, h_self, wph, wpl, deg,
                                                hn, hs, off);
    fill_kernel<<<NEDGES / 256, 256, 0, stream>>>(src, dst, off, rank, perm, gsrc);
    edge_kernel<<<1024, 256, 0, stream>>>(ef, wbh, wbl, b_edge, hn, perm, gsrc, msg);
    final_kernel<<<NNODES / 4, 256, 0, stream>>>(hs, msg, deg, off, wsT, wnT, out);
}

// Round 9
// 127.828 us; speedup vs baseline: 7.6250x; 2.1481x over previous
//
#include <hip/hip_runtime.h>
#include <hip/hip_bf16.h>

typedef __attribute__((ext_vector_type(8))) short bf16x8;
typedef __attribute__((ext_vector_type(4))) float f32x4;

#define NNODES 8192
#define NEDGES 65536
#define FIN 256
#define FOUT 64
#define EDIM 32

// workspace byte offsets
#define WS_HN    0x000000u   // 2 MB
#define WS_HS    0x200000u   // 2 MB
#define WS_MSG   0x400000u   // 16 MB (slot-order msg = s[e]*hn[src[e]])
#define WS_DEG   0x1400000u  // 32 KB
#define WS_OFF   0x1408000u  // 32 KB
#define WS_RANK  0x1410000u  // 256 KB
#define WS_PERM  0x1450000u  // 256 KB (slot -> edge id)
#define WS_GSRC  0x1490000u  // 256 KB (slot -> src node)
#define WS_WBI   0x14D0000u  // 512 KB bf16 W_edge hi/lo interleaved [col][kc][hi8|lo8]
#define WS_WPH   0x1550000u  // 32 KB bf16 W_preagg hi
#define WS_WPL   0x1558000u  // 32 KB bf16 W_preagg lo
#define WS_WST   0x1560000u  // 16 KB fp32 W_self^T
#define WS_WNT   0x1564000u  // 16 KB fp32 W_neigh^T

__device__ __forceinline__ unsigned short f2bf(float f) {
    unsigned u = __builtin_bit_cast(unsigned, f);
    u = (u + 0x7fffu + ((u >> 16) & 1u)) >> 16;   // RNE
    return (unsigned short)u;
}
__device__ __forceinline__ float bf2f(unsigned short h) {
    unsigned u = ((unsigned)h) << 16;
    return __builtin_bit_cast(float, u);
}
// split fp32 -> hi bf16 + lo bf16 (residual); x ~= hi + lo to ~2^-17 rel
__device__ __forceinline__ void split8(float4 v0, float4 v1, bf16x8& hi, bf16x8& lo) {
    float x[8] = {v0.x, v0.y, v0.z, v0.w, v1.x, v1.y, v1.z, v1.w};
    #pragma unroll
    for (int j = 0; j < 8; ++j) {
        unsigned short h = f2bf(x[j]);
        hi[j] = (short)h;
        lo[j] = (short)f2bf(x[j] - bf2f(h));
    }
}

// ---------------- K1: prep (weight transforms, hi+lo split) || count ----------------
// W_edge interleaved layout (ushort units):
//   element (col, k):  hi at col*64 + (k>>3)*16 + (k&7),  lo at +8
__global__ __launch_bounds__(256) void prep_count_kernel(
    const float* __restrict__ W_edge,
    const float* __restrict__ W_preagg,
    const float* __restrict__ W_self,
    const float* __restrict__ W_neigh,
    const int* __restrict__ dst,
    unsigned short* __restrict__ wbi,
    unsigned short* __restrict__ wph,
    unsigned short* __restrict__ wpl,
    float* __restrict__ wsT,
    float* __restrict__ wnT,
    int* __restrict__ deg,
    int* __restrict__ rank) {
    int b = blockIdx.x, t = threadIdx.x;
    if (b < 512) {
        int i = b * 256 + t;
        if (i < FOUT * FOUT * EDIM) {                 // 131072; i = col*32 + k
            int col = i >> 5, k = i & 31;
            float wv = W_edge[i];
            unsigned short h = f2bf(wv);
            unsigned short l = f2bf(wv - bf2f(h));
            int base = col * 64 + (k >> 3) * 16 + (k & 7);
            wbi[base] = h;
            wbi[base + 8] = l;
        }
        if (i < FOUT * FIN) {                         // 16384, row-major [64][256]
            float wv = W_preagg[i];
            unsigned short h = f2bf(wv);
            wph[i] = h;
            wpl[i] = f2bf(wv - bf2f(h));
        }
        if (i < FOUT * FOUT) {                        // 4096
            int o = i >> 6, k = i & 63;
            wsT[k * FOUT + o] = W_self[i];
            wnT[k * FOUT + o] = W_neigh[i];
        }
    } else {
        int e = (b - 512) * 256 + t;
        rank[e] = atomicAdd(deg + dst[e], 1);
    }
}

// ---------------- K2: preagg as split-bf16 MFMA GEMM (no LDS) || scan ----------------
__global__ __launch_bounds__(256) void preagg_scan_kernel(
    const float* __restrict__ h_neigh,
    const float* __restrict__ h_self,
    const unsigned short* __restrict__ wph,
    const unsigned short* __restrict__ wpl,
    const int* __restrict__ deg,
    float* __restrict__ hn,
    float* __restrict__ hs,
    int* __restrict__ off) {
    __shared__ int wsum[4];
    int b = blockIdx.x, t = threadIdx.x;
    if (b == 256) {                      // scan, single block
        int lane = t & 63, w = t >> 6;
        int base = t * 32;
        int loc[32];
        int s = 0;
        #pragma unroll
        for (int i = 0; i < 32; ++i) { loc[i] = s; s += deg[base + i]; }
        int v = s;
        #pragma unroll
        for (int d = 1; d < 64; d <<= 1) {
            int u = __shfl_up(v, d);
            if (lane >= d) v += u;
        }
        if (lane == 63) wsum[w] = v;
        int threadExcl = v - s;
        __syncthreads();
        int wexcl = 0;
        for (int i = 0; i < w; ++i) wexcl += wsum[i];
        int tbase = wexcl + threadExcl;
        #pragma unroll
        for (int i = 0; i < 32; ++i) off[base + i] = tbase + loc[i];
        return;
    }
    int w = t >> 6, lane = t & 63;
    int rowm = lane & 15, kc = lane >> 4;
    int g0 = (b * 4 + w) * 16;           // global row group [g0, g0+16)
    const float* hsrc;
    float* outp;
    int r0;
    if (g0 < NNODES) { hsrc = h_neigh; outp = hn; r0 = g0; }
    else             { hsrc = h_self;  outp = hs; r0 = g0 - NNODES; }
    const float* arow = hsrc + (size_t)(r0 + rowm) * FIN;

    f32x4 acc[4];
    #pragma unroll
    for (int ot = 0; ot < 4; ++ot) acc[ot] = f32x4{0.f, 0.f, 0.f, 0.f};

    #pragma unroll 2
    for (int ks = 0; ks < 8; ++ks) {
        const float* p = arow + ks * 32 + kc * 8;
        float4 v0 = reinterpret_cast<const float4*>(p)[0];
        float4 v1 = reinterpret_cast<const float4*>(p)[1];
        bf16x8 ahi, alo;
        split8(v0, v1, ahi, alo);
        #pragma unroll
        for (int ot = 0; ot < 4; ++ot) {
            int woff = (ot * 16 + rowm) * FIN + ks * 32 + kc * 8;
            bf16x8 bh = *reinterpret_cast<const bf16x8*>(wph + woff);
            bf16x8 bl = *reinterpret_cast<const bf16x8*>(wpl + woff);
            acc[ot] = __builtin_amdgcn_mfma_f32_16x16x32_bf16(ahi, bh, acc[ot], 0, 0, 0);
            acc[ot] = __builtin_amdgcn_mfma_f32_16x16x32_bf16(alo, bh, acc[ot], 0, 0, 0);
            acc[ot] = __builtin_amdgcn_mfma_f32_16x16x32_bf16(ahi, bl, acc[ot], 0, 0, 0);
        }
    }
    #pragma unroll
    for (int ot = 0; ot < 4; ++ot)
        #pragma unroll
        for (int r = 0; r < 4; ++r)
            outp[(size_t)(r0 + kc * 4 + r) * FOUT + ot * 16 + rowm] =
                fmaxf(acc[ot][r], 0.f);
}

// ---------------- K3: fill slot tables ----------------
__global__ void fill_kernel(const int* __restrict__ src,
                            const int* __restrict__ dst,
                            const int* __restrict__ off,
                            const int* __restrict__ rank,
                            int* __restrict__ perm,
                            int* __restrict__ gsrc) {
    int e = blockIdx.x * 256 + threadIdx.x;
    int slot = off[dst[e]] + rank[e];
    perm[slot] = e;
    gsrc[slot] = src[e];
}

// ---------------- K4: edge GEMM (split-bf16, 3-MFMA chain), slot order --------------
// block = 256 thr = 4 waves = 4 col-quarters (cw); block owns 64 slots; grid 1024.
// RUNTIME g-loop, unroll 2, pointer increments — prevents the full-unroll register
// blow-up that spilled rounds 6 & 8 (VGPR 256, 450 MB scratch writes).
__global__ __launch_bounds__(256) void edge_kernel(
    const float* __restrict__ ef,
    const unsigned short* __restrict__ wbi,
    const float* __restrict__ b_edge,
    const float* __restrict__ hn,
    const int* __restrict__ perm,
    const int* __restrict__ gsrc,
    float* __restrict__ msg) {
    int t = threadIdx.x;
    int cw = t >> 6, lane = t & 63;
    int rowm = lane & 15, kc = lane >> 4, k0 = kc * 8;
    int e0 = blockIdx.x * 64;
    int colbase = cw * 16 + rowm;

    // A fragments (hi+lo): lane holds ef[perm[e0 + tt*16 + rowm]][k0 .. k0+8)
    bf16x8 ahi[4], alo[4];
    #pragma unroll
    for (int tt = 0; tt < 4; ++tt) {
        int eidx = perm[e0 + tt * 16 + rowm];
        const float* p = ef + (size_t)eidx * EDIM + k0;
        float4 v0 = reinterpret_cast<const float4*>(p)[0];
        float4 v1 = reinterpret_cast<const float4*>(p)[1];
        split8(v0, v1, ahi[tt], alo[tt]);
    }

    f32x4 sacc[4];
    #pragma unroll
    for (int tt = 0; tt < 4; ++tt) sacc[tt] = f32x4{0.f, 0.f, 0.f, 0.f};
    const f32x4 z4 = {0.f, 0.f, 0.f, 0.f};

    // per-lane W pointer for g=0: ushort offset = (g*64 + colbase)*64 + kc*16
    const unsigned short* wp = wbi + ((size_t)colbase * 64 + kc * 16);
    const float* bp = b_edge + colbase;

    #pragma unroll 2
    for (int g = 0; g < 64; ++g) {
        bf16x8 bh = *reinterpret_cast<const bf16x8*>(wp);
        bf16x8 bl = *reinterpret_cast<const bf16x8*>(wp + 8);
        float bias = *bp;
        wp += 4096;                      // next col-group: 64 cols * 64 ushorts
        bp += 64;
        f32x4 cin = {bias, bias, bias, bias};
        #pragma unroll
        for (int tt = 0; tt < 4; ++tt) {
            // ew = Ahi*Bhi + Alo*Bhi + Ahi*Blo (+ O(2^-18)) + bias
            f32x4 d = __builtin_amdgcn_mfma_f32_16x16x32_bf16(ahi[tt], bh, cin, 0, 0, 0);
            d = __builtin_amdgcn_mfma_f32_16x16x32_bf16(alo[tt], bh, d, 0, 0, 0);
            d = __builtin_amdgcn_mfma_f32_16x16x32_bf16(ahi[tt], bl, d, 0, 0, 0);
            sacc[tt] += __builtin_elementwise_max(d, z4);   // relu + i-fold
        }
    }

    // epilogue: msg[slot][j] = s * hn[gsrc[slot]][j]; 64B contiguous per 1/4-wave
    #pragma unroll
    for (int tt = 0; tt < 4; ++tt) {
        #pragma unroll
        for (int r = 0; r < 4; ++r) {
            int slot = e0 + tt * 16 + kc * 4 + r;
            int se = gsrc[slot];
            float hv = hn[(size_t)se * FOUT + colbase];
            msg[(size_t)slot * FOUT + colbase] = sacc[tt][r] * hv;
        }
    }
}

// ---------------- K5: final — streaming mean over contiguous slots + two FCs --------
__global__ __launch_bounds__(256) void final_kernel(
    const float* __restrict__ hs,
    const float* __restrict__ msg,
    const int* __restrict__ deg,
    const int* __restrict__ off,
    const float* __restrict__ wsT,
    const float* __restrict__ wnT,
    float* __restrict__ out) {
    __shared__ float sm[4][2][FOUT];
    int t = threadIdx.x, w = t >> 6, lane = t & 63;
    int n = blockIdx.x * 4 + w;
    int o0 = off[n], d = deg[n];
    const float* mp = msg + (size_t)o0 * FOUT + lane;
    float acc = 0.f;
    int i = 0;
    for (; i + 4 <= d; i += 4) {
        float m0 = mp[(size_t)(i + 0) * FOUT];
        float m1 = mp[(size_t)(i + 1) * FOUT];
        float m2 = mp[(size_t)(i + 2) * FOUT];
        float m3 = mp[(size_t)(i + 3) * FOUT];
        acc += (m0 + m1) + (m2 + m3);
    }
    for (; i < d; ++i) acc += mp[(size_t)i * FOUT];
    float neigh = acc / fmaxf((float)d, 1.f);
    sm[w][0][lane] = neigh;
    sm[w][1][lane] = hs[(size_t)n * FOUT + lane];
    __syncthreads();
    float a1 = 0.f, a2 = 0.f;
    #pragma unroll 8
    for (int k = 0; k < FOUT; ++k) {
        a1 = fmaf(sm[w][1][k], wsT[k * FOUT + lane], a1);
        a2 = fmaf(sm[w][0][k], wnT[k * FOUT + lane], a2);
    }
    out[(size_t)n * FOUT + lane] = fmaxf(fmaxf(a1, 0.f) + fmaxf(a2, 0.f), 0.f);
}

extern "C" void kernel_launch(void* const* d_in, const int* in_sizes, int n_in,
                              void* d_out, int out_size, void* d_ws, size_t ws_size,
                              hipStream_t stream) {
    const float* h_neigh  = (const float*)d_in[0];
    const float* h_self   = (const float*)d_in[1];
    const float* ef       = (const float*)d_in[2];
    const float* W_preagg = (const float*)d_in[3];
    const float* W_self   = (const float*)d_in[4];
    const float* W_neigh  = (const float*)d_in[5];
    const float* W_edge   = (const float*)d_in[6];
    const float* b_edge   = (const float*)d_in[7];
    const int*   src      = (const int*)d_in[8];
    const int*   dst      = (const int*)d_in[9];
    float* out = (float*)d_out;
    char* ws = (char*)d_ws;

    float* hn    = (float*)(ws + WS_HN);
    float* hs    = (float*)(ws + WS_HS);
    float* msg   = (float*)(ws + WS_MSG);
    int*   deg   = (int*)(ws + WS_DEG);
    int*   off   = (int*)(ws + WS_OFF);
    int*   rank  = (int*)(ws + WS_RANK);
    int*   perm  = (int*)(ws + WS_PERM);
    int*   gsrc  = (int*)(ws + WS_GSRC);
    unsigned short* wbi = (unsigned short*)(ws + WS_WBI);
    unsigned short* wph = (unsigned short*)(ws + WS_WPH);
    unsigned short* wpl = (unsigned short*)(ws + WS_WPL);
    float* wsT   = (float*)(ws + WS_WST);
    float* wnT   = (float*)(ws + WS_WNT);

    // zero deg every call (count accumulates via atomics)
    hipMemsetAsync(ws + WS_DEG, 0, 0x8000, stream);

    prep_count_kernel<<<768, 256, 0, stream>>>(W_edge, W_preagg, W_self, W_neigh,
                                               dst, wbi, wph, wpl, wsT, wnT,
                                               deg, rank);
    preagg_scan_kernel<<<257, 256, 0, stream>>>(h_neigh, h_self, wph, wpl, deg,
                                                hn, hs, off);
    fill_kernel<<<NEDGES / 256, 256, 0, stream>>>(src, dst, off, rank, perm, gsrc);
    edge_kernel<<<1024, 256, 0, stream>>>(ef, wbi, b_edge, hn, perm, gsrc, msg);
    final_kernel<<<NNODES / 4, 256, 0, stream>>>(hs, msg, deg, off, wsT, wnT, out);
}

// Round 10
// 88.091 us; speedup vs baseline: 11.0644x; 1.4511x over previous
//
#include <hip/hip_runtime.h>
#include <hip/hip_bf16.h>

typedef __attribute__((ext_vector_type(8))) short bf16x8;
typedef __attribute__((ext_vector_type(8))) _Float16 f16x8;
typedef __attribute__((ext_vector_type(4))) float f32x4;

#define NNODES 8192
#define NEDGES 65536
#define FIN 256
#define FOUT 64
#define EDIM 32

// workspace byte offsets
#define WS_HN    0x000000u   // 2 MB
#define WS_HS    0x200000u   // 2 MB
#define WS_MSG   0x400000u   // 16 MB (slot-order msg = s[e]*hn[src[e]])
#define WS_DEG   0x1400000u  // 32 KB
#define WS_OFF   0x1408000u  // 32 KB
#define WS_RANK  0x1410000u  // 256 KB
#define WS_PERM  0x1450000u  // 256 KB (slot -> edge id)
#define WS_GSRC  0x1490000u  // 256 KB (slot -> src node)
#define WS_WEH   0x14D0000u  // 256 KB fp16 W_edge [col][k] (same flat index as input)
#define WS_WPH   0x1550000u  // 32 KB bf16 W_preagg hi
#define WS_WPL   0x1558000u  // 32 KB bf16 W_preagg lo
#define WS_WST   0x1560000u  // 16 KB fp32 W_self^T
#define WS_WNT   0x1564000u  // 16 KB fp32 W_neigh^T

__device__ __forceinline__ unsigned short f2bf(float f) {
    unsigned u = __builtin_bit_cast(unsigned, f);
    u = (u + 0x7fffu + ((u >> 16) & 1u)) >> 16;   // RNE
    return (unsigned short)u;
}
__device__ __forceinline__ float bf2f(unsigned short h) {
    unsigned u = ((unsigned)h) << 16;
    return __builtin_bit_cast(float, u);
}
// split fp32 -> hi bf16 + lo bf16 (residual); x ~= hi + lo to ~2^-17 rel
__device__ __forceinline__ void split8(float4 v0, float4 v1, bf16x8& hi, bf16x8& lo) {
    float x[8] = {v0.x, v0.y, v0.z, v0.w, v1.x, v1.y, v1.z, v1.w};
    #pragma unroll
    for (int j = 0; j < 8; ++j) {
        unsigned short h = f2bf(x[j]);
        hi[j] = (short)h;
        lo[j] = (short)f2bf(x[j] - bf2f(h));
    }
}
__device__ __forceinline__ f16x8 pack8h(float4 v0, float4 v1) {
    f16x8 r;
    r[0] = (_Float16)v0.x; r[1] = (_Float16)v0.y;
    r[2] = (_Float16)v0.z; r[3] = (_Float16)v0.w;
    r[4] = (_Float16)v1.x; r[5] = (_Float16)v1.y;
    r[6] = (_Float16)v1.z; r[7] = (_Float16)v1.w;
    return r;
}

// ---------------- K1: prep (weight transforms) || count ----------------
__global__ __launch_bounds__(256) void prep_count_kernel(
    const float* __restrict__ W_edge,
    const float* __restrict__ W_preagg,
    const float* __restrict__ W_self,
    const float* __restrict__ W_neigh,
    const int* __restrict__ dst,
    _Float16* __restrict__ weh,
    unsigned short* __restrict__ wph,
    unsigned short* __restrict__ wpl,
    float* __restrict__ wsT,
    float* __restrict__ wnT,
    int* __restrict__ deg,
    int* __restrict__ rank) {
    int b = blockIdx.x, t = threadIdx.x;
    if (b < 512) {
        int i = b * 256 + t;
        if (i < FOUT * FOUT * EDIM)                   // 131072; layout identical to input
            weh[i] = (_Float16)W_edge[i];
        if (i < FOUT * FIN) {                         // 16384, row-major [64][256]
            float wv = W_preagg[i];
            unsigned short h = f2bf(wv);
            wph[i] = h;
            wpl[i] = f2bf(wv - bf2f(h));
        }
        if (i < FOUT * FOUT) {                        // 4096
            int o = i >> 6, k = i & 63;
            wsT[k * FOUT + o] = W_self[i];
            wnT[k * FOUT + o] = W_neigh[i];
        }
    } else {
        int e = (b - 512) * 256 + t;
        rank[e] = atomicAdd(deg + dst[e], 1);
    }
}

// ---------------- K2: preagg as split-bf16 MFMA GEMM (no LDS) || scan ----------------
__global__ __launch_bounds__(256) void preagg_scan_kernel(
    const float* __restrict__ h_neigh,
    const float* __restrict__ h_self,
    const unsigned short* __restrict__ wph,
    const unsigned short* __restrict__ wpl,
    const int* __restrict__ deg,
    float* __restrict__ hn,
    float* __restrict__ hs,
    int* __restrict__ off) {
    __shared__ int wsum[4];
    int b = blockIdx.x, t = threadIdx.x;
    if (b == 256) {                      // scan, single block
        int lane = t & 63, w = t >> 6;
        int base = t * 32;
        int loc[32];
        int s = 0;
        #pragma unroll
        for (int i = 0; i < 32; ++i) { loc[i] = s; s += deg[base + i]; }
        int v = s;
        #pragma unroll
        for (int d = 1; d < 64; d <<= 1) {
            int u = __shfl_up(v, d);
            if (lane >= d) v += u;
        }
        if (lane == 63) wsum[w] = v;
        int threadExcl = v - s;
        __syncthreads();
        int wexcl = 0;
        for (int i = 0; i < w; ++i) wexcl += wsum[i];
        int tbase = wexcl + threadExcl;
        #pragma unroll
        for (int i = 0; i < 32; ++i) off[base + i] = tbase + loc[i];
        return;
    }
    int w = t >> 6, lane = t & 63;
    int rowm = lane & 15, kc = lane >> 4;
    int g0 = (b * 4 + w) * 16;           // global row group [g0, g0+16)
    const float* hsrc;
    float* outp;
    int r0;
    if (g0 < NNODES) { hsrc = h_neigh; outp = hn; r0 = g0; }
    else             { hsrc = h_self;  outp = hs; r0 = g0 - NNODES; }
    const float* arow = hsrc + (size_t)(r0 + rowm) * FIN;

    f32x4 acc[4];
    #pragma unroll
    for (int ot = 0; ot < 4; ++ot) acc[ot] = f32x4{0.f, 0.f, 0.f, 0.f};

    #pragma unroll 2
    for (int ks = 0; ks < 8; ++ks) {
        const float* p = arow + ks * 32 + kc * 8;
        float4 v0 = reinterpret_cast<const float4*>(p)[0];
        float4 v1 = reinterpret_cast<const float4*>(p)[1];
        bf16x8 ahi, alo;
        split8(v0, v1, ahi, alo);
        #pragma unroll
        for (int ot = 0; ot < 4; ++ot) {
            int woff = (ot * 16 + rowm) * FIN + ks * 32 + kc * 8;
            bf16x8 bh = *reinterpret_cast<const bf16x8*>(wph + woff);
            bf16x8 bl = *reinterpret_cast<const bf16x8*>(wpl + woff);
            acc[ot] = __builtin_amdgcn_mfma_f32_16x16x32_bf16(ahi, bh, acc[ot], 0, 0, 0);
            acc[ot] = __builtin_amdgcn_mfma_f32_16x16x32_bf16(alo, bh, acc[ot], 0, 0, 0);
            acc[ot] = __builtin_amdgcn_mfma_f32_16x16x32_bf16(ahi, bl, acc[ot], 0, 0, 0);
        }
    }
    #pragma unroll
    for (int ot = 0; ot < 4; ++ot)
        #pragma unroll
        for (int r = 0; r < 4; ++r)
            outp[(size_t)(r0 + kc * 4 + r) * FOUT + ot * 16 + rowm] =
                fmaxf(acc[ot][r], 0.f);
}

// ---------------- K3: fill slot tables ----------------
__global__ void fill_kernel(const int* __restrict__ src,
                            const int* __restrict__ dst,
                            const int* __restrict__ off,
                            const int* __restrict__ rank,
                            int* __restrict__ perm,
                            int* __restrict__ gsrc) {
    int e = blockIdx.x * 256 + threadIdx.x;
    int slot = off[dst[e]] + rank[e];
    perm[slot] = e;
    gsrc[slot] = src[e];
}

// ---------------- K4: edge GEMM (fp16 single-pass), slot order, fused hn-mul --------
// block = 256 thr = 4 waves = 4 col-quarters (cw); block owns 64 slots; grid 1024.
// Runtime g-loop, unroll 4, pointer increments (spill lessons r6/r8). One dense
// 16B B-load per lane per g (wave covers 1KB contiguous of the fp16 W table).
__global__ __launch_bounds__(256) void edge_kernel(
    const float* __restrict__ ef,
    const _Float16* __restrict__ weh,
    const float* __restrict__ b_edge,
    const float* __restrict__ hn,
    const int* __restrict__ perm,
    const int* __restrict__ gsrc,
    float* __restrict__ msg) {
    int t = threadIdx.x;
    int cw = t >> 6, lane = t & 63;
    int rowm = lane & 15, kc = lane >> 4, k0 = kc * 8;
    int e0 = blockIdx.x * 64;
    int colbase = cw * 16 + rowm;

    // A fragments (fp16): lane holds ef[perm[e0 + tt*16 + rowm]][k0 .. k0+8)
    f16x8 a[4];
    #pragma unroll
    for (int tt = 0; tt < 4; ++tt) {
        int eidx = perm[e0 + tt * 16 + rowm];
        const float* p = ef + (size_t)eidx * EDIM + k0;
        float4 v0 = reinterpret_cast<const float4*>(p)[0];
        float4 v1 = reinterpret_cast<const float4*>(p)[1];
        a[tt] = pack8h(v0, v1);
    }

    f32x4 sacc[4];
    #pragma unroll
    for (int tt = 0; tt < 4; ++tt) sacc[tt] = f32x4{0.f, 0.f, 0.f, 0.f};
    const f32x4 z4 = {0.f, 0.f, 0.f, 0.f};

    // per-lane W pointer for g=0: fp16 offset = (g*64 + colbase)*32 + kc*8
    const _Float16* wp = weh + ((size_t)colbase * 32 + kc * 8);
    const float* bp = b_edge + colbase;

    #pragma unroll 4
    for (int g = 0; g < 64; ++g) {
        f16x8 bh = *reinterpret_cast<const f16x8*>(wp);
        float bias = *bp;
        wp += 2048;                      // next col-group: 64 cols * 32 fp16
        bp += 64;
        f32x4 cin = {bias, bias, bias, bias};
        #pragma unroll
        for (int tt = 0; tt < 4; ++tt) {
            f32x4 d = __builtin_amdgcn_mfma_f32_16x16x32_f16(a[tt], bh, cin, 0, 0, 0);
            sacc[tt] += __builtin_elementwise_max(d, z4);   // relu + i-fold
        }
    }

    // epilogue: msg[slot][j] = s * hn[gsrc[slot]][j]; 64B contiguous per 1/4-wave
    #pragma unroll
    for (int tt = 0; tt < 4; ++tt) {
        #pragma unroll
        for (int r = 0; r < 4; ++r) {
            int slot = e0 + tt * 16 + kc * 4 + r;
            int se = gsrc[slot];
            float hv = hn[(size_t)se * FOUT + colbase];
            msg[(size_t)slot * FOUT + colbase] = sacc[tt][r] * hv;
        }
    }
}

// ---------------- K5: final — streaming mean over contiguous slots + two FCs --------
__global__ __launch_bounds__(256) void final_kernel(
    const float* __restrict__ hs,
    const float* __restrict__ msg,
    const int* __restrict__ deg,
    const int* __restrict__ off,
    const float* __restrict__ wsT,
    const float* __restrict__ wnT,
    float* __restrict__ out) {
    __shared__ float sm[4][2][FOUT];
    int t = threadIdx.x, w = t >> 6, lane = t & 63;
    int n = blockIdx.x * 4 + w;
    int o0 = off[n], d = deg[n];
    const float* mp = msg + (size_t)o0 * FOUT + lane;
    float acc = 0.f;
    int i = 0;
    for (; i + 4 <= d; i += 4) {
        float m0 = mp[(size_t)(i + 0) * FOUT];
        float m1 = mp[(size_t)(i + 1) * FOUT];
        float m2 = mp[(size_t)(i + 2) * FOUT];
        float m3 = mp[(size_t)(i + 3) * FOUT];
        acc += (m0 + m1) + (m2 + m3);
    }
    for (; i < d; ++i) acc += mp[(size_t)i * FOUT];
    float neigh = acc / fmaxf((float)d, 1.f);
    sm[w][0][lane] = neigh;
    sm[w][1][lane] = hs[(size_t)n * FOUT + lane];
    __syncthreads();
    float a1 = 0.f, a2 = 0.f;
    #pragma unroll 8
    for (int k = 0; k < FOUT; ++k) {
        a1 = fmaf(sm[w][1][k], wsT[k * FOUT + lane], a1);
        a2 = fmaf(sm[w][0][k], wnT[k * FOUT + lane], a2);
    }
    out[(size_t)n * FOUT + lane] = fmaxf(fmaxf(a1, 0.f) + fmaxf(a2, 0.f), 0.f);
}

extern "C" void kernel_launch(void* const* d_in, const int* in_sizes, int n_in,
                              void* d_out, int out_size, void* d_ws, size_t ws_size,
                              hipStream_t stream) {
    const float* h_neigh  = (const float*)d_in[0];
    const float* h_self   = (const float*)d_in[1];
    const float* ef       = (const float*)d_in[2];
    const float* W_preagg = (const float*)d_in[3];
    const float* W_self   = (const float*)d_in[4];
    const float* W_neigh  = (const float*)d_in[5];
    const float* W_edge   = (const float*)d_in[6];
    const float* b_edge   = (const float*)d_in[7];
    const int*   src      = (const int*)d_in[8];
    const int*   dst      = (const int*)d_in[9];
    float* out = (float*)d_out;
    char* ws = (char*)d_ws;

    float* hn    = (float*)(ws + WS_HN);
    float* hs    = (float*)(ws + WS_HS);
    float* msg   = (float*)(ws + WS_MSG);
    int*   deg   = (int*)(ws + WS_DEG);
    int*   off   = (int*)(ws + WS_OFF);
    int*   rank  = (int*)(ws + WS_RANK);
    int*   perm  = (int*)(ws + WS_PERM);
    int*   gsrc  = (int*)(ws + WS_GSRC);
    _Float16* weh = (_Float16*)(ws + WS_WEH);
    unsigned short* wph = (unsigned short*)(ws + WS_WPH);
    unsigned short* wpl = (unsigned short*)(ws + WS_WPL);
    float* wsT   = (float*)(ws + WS_WST);
    float* wnT   = (float*)(ws + WS_WNT);

    // zero deg every call (count accumulates via atomics)
    hipMemsetAsync(ws + WS_DEG, 0, 0x8000, stream);

    prep_count_kernel<<<768, 256, 0, stream>>>(W_edge, W_preagg, W_self, W_neigh,
                                               dst, weh, wph, wpl, wsT, wnT,
                                               deg, rank);
    preagg_scan_kernel<<<257, 256, 0, stream>>>(h_neigh, h_self, wph, wpl, deg,
                                                hn, hs, off);
    fill_kernel<<<NEDGES / 256, 256, 0, stream>>>(src, dst, off, rank, perm, gsrc);
    edge_kernel<<<1024, 256, 0, stream>>>(ef, weh, b_edge, hn, perm, gsrc, msg);
    final_kernel<<<NNODES / 4, 256, 0, stream>>>(hs, msg, deg, off, wsT, wnT, out);
}

// Round 11
// 87.562 us; speedup vs baseline: 11.1313x; 1.0060x over previous
//
#include <hip/hip_runtime.h>
#include <hip/hip_bf16.h>

typedef __attribute__((ext_vector_type(8))) short bf16x8;
typedef __attribute__((ext_vector_type(8))) _Float16 f16x8;
typedef __attribute__((ext_vector_type(4))) float f32x4;

#define NNODES 8192
#define NEDGES 65536
#define FIN 256
#define FOUT 64
#define EDIM 32

// workspace byte offsets
#define WS_HN    0x000000u   // 2 MB
#define WS_HS    0x200000u   // 2 MB
#define WS_MSG   0x400000u   // 16 MB (slot-order msg = s[e]*hn[src[e]])
#define WS_DEG   0x1400000u  // 32 KB
#define WS_OFF   0x1408000u  // 32 KB
#define WS_RANK  0x1410000u  // 256 KB
#define WS_PERM  0x1450000u  // 256 KB (slot -> edge id)
#define WS_GSRC  0x1490000u  // 256 KB (slot -> src node)
#define WS_WEH   0x14D0000u  // 256 KB fp16 W_edge [col][k] (same flat index as input)
#define WS_WPH   0x1550000u  // 32 KB bf16 W_preagg hi
#define WS_WPL   0x1558000u  // 32 KB bf16 W_preagg lo
#define WS_WST   0x1560000u  // 16 KB fp32 W_self^T
#define WS_WNT   0x1564000u  // 16 KB fp32 W_neigh^T

__device__ __forceinline__ unsigned short f2bf(float f) {
    unsigned u = __builtin_bit_cast(unsigned, f);
    u = (u + 0x7fffu + ((u >> 16) & 1u)) >> 16;   // RNE
    return (unsigned short)u;
}
__device__ __forceinline__ float bf2f(unsigned short h) {
    unsigned u = ((unsigned)h) << 16;
    return __builtin_bit_cast(float, u);
}
// split fp32 -> hi bf16 + lo bf16 (residual); x ~= hi + lo to ~2^-17 rel
__device__ __forceinline__ void split8(float4 v0, float4 v1, bf16x8& hi, bf16x8& lo) {
    float x[8] = {v0.x, v0.y, v0.z, v0.w, v1.x, v1.y, v1.z, v1.w};
    #pragma unroll
    for (int j = 0; j < 8; ++j) {
        unsigned short h = f2bf(x[j]);
        hi[j] = (short)h;
        lo[j] = (short)f2bf(x[j] - bf2f(h));
    }
}
__device__ __forceinline__ f16x8 pack8h(float4 v0, float4 v1) {
    f16x8 r;
    r[0] = (_Float16)v0.x; r[1] = (_Float16)v0.y;
    r[2] = (_Float16)v0.z; r[3] = (_Float16)v0.w;
    r[4] = (_Float16)v1.x; r[5] = (_Float16)v1.y;
    r[6] = (_Float16)v1.z; r[7] = (_Float16)v1.w;
    return r;
}

// ---------------- K1: prep (weight transforms) || count ----------------
__global__ __launch_bounds__(256) void prep_count_kernel(
    const float* __restrict__ W_edge,
    const float* __restrict__ W_preagg,
    const float* __restrict__ W_self,
    const float* __restrict__ W_neigh,
    const int* __restrict__ dst,
    _Float16* __restrict__ weh,
    unsigned short* __restrict__ wph,
    unsigned short* __restrict__ wpl,
    float* __restrict__ wsT,
    float* __restrict__ wnT,
    int* __restrict__ deg,
    int* __restrict__ rank) {
    int b = blockIdx.x, t = threadIdx.x;
    if (b < 512) {
        int i = b * 256 + t;
        if (i < FOUT * FOUT * EDIM)                   // 131072; layout identical to input
            weh[i] = (_Float16)W_edge[i];
        if (i < FOUT * FIN) {                         // 16384, row-major [64][256]
            float wv = W_preagg[i];
            unsigned short h = f2bf(wv);
            wph[i] = h;
            wpl[i] = f2bf(wv - bf2f(h));
        }
        if (i < FOUT * FOUT) {                        // 4096
            int o = i >> 6, k = i & 63;
            wsT[k * FOUT + o] = W_self[i];
            wnT[k * FOUT + o] = W_neigh[i];
        }
    } else {
        int e = (b - 512) * 256 + t;
        rank[e] = atomicAdd(deg + dst[e], 1);
    }
}

// ---------------- K2: preagg as split-bf16 MFMA GEMM (no LDS) || scan ----------------
__global__ __launch_bounds__(256) void preagg_scan_kernel(
    const float* __restrict__ h_neigh,
    const float* __restrict__ h_self,
    const unsigned short* __restrict__ wph,
    const unsigned short* __restrict__ wpl,
    const int* __restrict__ deg,
    float* __restrict__ hn,
    float* __restrict__ hs,
    int* __restrict__ off) {
    __shared__ int wsum[4];
    int b = blockIdx.x, t = threadIdx.x;
    if (b == 256) {                      // scan, single block
        int lane = t & 63, w = t >> 6;
        int base = t * 32;
        int loc[32];
        int s = 0;
        #pragma unroll
        for (int i = 0; i < 32; ++i) { loc[i] = s; s += deg[base + i]; }
        int v = s;
        #pragma unroll
        for (int d = 1; d < 64; d <<= 1) {
            int u = __shfl_up(v, d);
            if (lane >= d) v += u;
        }
        if (lane == 63) wsum[w] = v;
        int threadExcl = v - s;
        __syncthreads();
        int wexcl = 0;
        for (int i = 0; i < w; ++i) wexcl += wsum[i];
        int tbase = wexcl + threadExcl;
        #pragma unroll
        for (int i = 0; i < 32; ++i) off[base + i] = tbase + loc[i];
        return;
    }
    int w = t >> 6, lane = t & 63;
    int rowm = lane & 15, kc = lane >> 4;
    int g0 = (b * 4 + w) * 16;           // global row group [g0, g0+16)
    const float* hsrc;
    float* outp;
    int r0;
    if (g0 < NNODES) { hsrc = h_neigh; outp = hn; r0 = g0; }
    else             { hsrc = h_self;  outp = hs; r0 = g0 - NNODES; }
    const float* arow = hsrc + (size_t)(r0 + rowm) * FIN;

    f32x4 acc[4];
    #pragma unroll
    for (int ot = 0; ot < 4; ++ot) acc[ot] = f32x4{0.f, 0.f, 0.f, 0.f};

    #pragma unroll 2
    for (int ks = 0; ks < 8; ++ks) {
        const float* p = arow + ks * 32 + kc * 8;
        float4 v0 = reinterpret_cast<const float4*>(p)[0];
        float4 v1 = reinterpret_cast<const float4*>(p)[1];
        bf16x8 ahi, alo;
        split8(v0, v1, ahi, alo);
        #pragma unroll
        for (int ot = 0; ot < 4; ++ot) {
            int woff = (ot * 16 + rowm) * FIN + ks * 32 + kc * 8;
            bf16x8 bh = *reinterpret_cast<const bf16x8*>(wph + woff);
            bf16x8 bl = *reinterpret_cast<const bf16x8*>(wpl + woff);
            acc[ot] = __builtin_amdgcn_mfma_f32_16x16x32_bf16(ahi, bh, acc[ot], 0, 0, 0);
            acc[ot] = __builtin_amdgcn_mfma_f32_16x16x32_bf16(alo, bh, acc[ot], 0, 0, 0);
            acc[ot] = __builtin_amdgcn_mfma_f32_16x16x32_bf16(ahi, bl, acc[ot], 0, 0, 0);
        }
    }
    #pragma unroll
    for (int ot = 0; ot < 4; ++ot)
        #pragma unroll
        for (int r = 0; r < 4; ++r)
            outp[(size_t)(r0 + kc * 4 + r) * FOUT + ot * 16 + rowm] =
                fmaxf(acc[ot][r], 0.f);
}

// ---------------- K3: fill slot tables ----------------
__global__ void fill_kernel(const int* __restrict__ src,
                            const int* __restrict__ dst,
                            const int* __restrict__ off,
                            const int* __restrict__ rank,
                            int* __restrict__ perm,
                            int* __restrict__ gsrc) {
    int e = blockIdx.x * 256 + threadIdx.x;
    int slot = off[dst[e]] + rank[e];
    perm[slot] = e;
    gsrc[slot] = src[e];
}

// ---------------- K4: edge GEMM (fp16 single-pass), slot order, fused hn-mul --------
// block = 256 thr = 4 waves = 4 col-quarters (cw); block owns 32 slots (2 M-tiles);
// grid 2048 -> 8192 waves = 8 waves/SIMD (r10 was 4/SIMD at 31% occupancy, the cap).
// Runtime g-loop, unroll 4, pointer increments (spill lessons r6/r8).
__global__ __launch_bounds__(256) void edge_kernel(
    const float* __restrict__ ef,
    const _Float16* __restrict__ weh,
    const float* __restrict__ b_edge,
    const float* __restrict__ hn,
    const int* __restrict__ perm,
    const int* __restrict__ gsrc,
    float* __restrict__ msg) {
    int t = threadIdx.x;
    int cw = t >> 6, lane = t & 63;
    int rowm = lane & 15, kc = lane >> 4, k0 = kc * 8;
    int e0 = blockIdx.x * 32;
    int colbase = cw * 16 + rowm;

    // A fragments (fp16): lane holds ef[perm[e0 + tt*16 + rowm]][k0 .. k0+8)
    f16x8 a[2];
    #pragma unroll
    for (int tt = 0; tt < 2; ++tt) {
        int eidx = perm[e0 + tt * 16 + rowm];
        const float* p = ef + (size_t)eidx * EDIM + k0;
        float4 v0 = reinterpret_cast<const float4*>(p)[0];
        float4 v1 = reinterpret_cast<const float4*>(p)[1];
        a[tt] = pack8h(v0, v1);
    }

    f32x4 sacc[2];
    #pragma unroll
    for (int tt = 0; tt < 2; ++tt) sacc[tt] = f32x4{0.f, 0.f, 0.f, 0.f};
    const f32x4 z4 = {0.f, 0.f, 0.f, 0.f};

    // per-lane W pointer for g=0: fp16 offset = (g*64 + colbase)*32 + kc*8
    const _Float16* wp = weh + ((size_t)colbase * 32 + kc * 8);
    const float* bp = b_edge + colbase;

    #pragma unroll 4
    for (int g = 0; g < 64; ++g) {
        f16x8 bh = *reinterpret_cast<const f16x8*>(wp);
        float bias = *bp;
        wp += 2048;                      // next col-group: 64 cols * 32 fp16
        bp += 64;
        f32x4 cin = {bias, bias, bias, bias};
        #pragma unroll
        for (int tt = 0; tt < 2; ++tt) {
            f32x4 d = __builtin_amdgcn_mfma_f32_16x16x32_f16(a[tt], bh, cin, 0, 0, 0);
            sacc[tt] += __builtin_elementwise_max(d, z4);   // relu + i-fold
        }
    }

    // epilogue: msg[slot][j] = s * hn[gsrc[slot]][j]; 64B contiguous per 1/4-wave
    #pragma unroll
    for (int tt = 0; tt < 2; ++tt) {
        #pragma unroll
        for (int r = 0; r < 4; ++r) {
            int slot = e0 + tt * 16 + kc * 4 + r;
            int se = gsrc[slot];
            float hv = hn[(size_t)se * FOUT + colbase];
            msg[(size_t)slot * FOUT + colbase] = sacc[tt][r] * hv;
        }
    }
}

// ---------------- K5: final — streaming mean over contiguous slots + two FCs --------
__global__ __launch_bounds__(256) void final_kernel(
    const float* __restrict__ hs,
    const float* __restrict__ msg,
    const int* __restrict__ deg,
    const int* __restrict__ off,
    const float* __restrict__ wsT,
    const float* __restrict__ wnT,
    float* __restrict__ out) {
    __shared__ float sm[4][2][FOUT];
    int t = threadIdx.x, w = t >> 6, lane = t & 63;
    int n = blockIdx.x * 4 + w;
    int o0 = off[n], d = deg[n];
    const float* mp = msg + (size_t)o0 * FOUT + lane;
    float acc = 0.f;
    int i = 0;
    for (; i + 4 <= d; i += 4) {
        float m0 = mp[(size_t)(i + 0) * FOUT];
        float m1 = mp[(size_t)(i + 1) * FOUT];
        float m2 = mp[(size_t)(i + 2) * FOUT];
        float m3 = mp[(size_t)(i + 3) * FOUT];
        acc += (m0 + m1) + (m2 + m3);
    }
    for (; i < d; ++i) acc += mp[(size_t)i * FOUT];
    float neigh = acc / fmaxf((float)d, 1.f);
    sm[w][0][lane] = neigh;
    sm[w][1][lane] = hs[(size_t)n * FOUT + lane];
    __syncthreads();
    float a1 = 0.f, a2 = 0.f;
    #pragma unroll 8
    for (int k = 0; k < FOUT; ++k) {
        a1 = fmaf(sm[w][1][k], wsT[k * FOUT + lane], a1);
        a2 = fmaf(sm[w][0][k], wnT[k * FOUT + lane], a2);
    }
    out[(size_t)n * FOUT + lane] = fmaxf(fmaxf(a1, 0.f) + fmaxf(a2, 0.f), 0.f);
}

extern "C" void kernel_launch(void* const* d_in, const int* in_sizes, int n_in,
                              void* d_out, int out_size, void* d_ws, size_t ws_size,
                              hipStream_t stream) {
    const float* h_neigh  = (const float*)d_in[0];
    const float* h_self   = (const float*)d_in[1];
    const float* ef       = (const float*)d_in[2];
    const float* W_preagg = (const float*)d_in[3];
    const float* W_self   = (const float*)d_in[4];
    const float* W_neigh  = (const float*)d_in[5];
    const float* W_edge   = (const float*)d_in[6];
    const float* b_edge   = (const float*)d_in[7];
    const int*   src      = (const int*)d_in[8];
    const int*   dst      = (const int*)d_in[9];
    float* out = (float*)d_out;
    char* ws = (char*)d_ws;

    float* hn    = (float*)(ws + WS_HN);
    float* hs    = (float*)(ws + WS_HS);
    float* msg   = (float*)(ws + WS_MSG);
    int*   deg   = (int*)(ws + WS_DEG);
    int*   off   = (int*)(ws + WS_OFF);
    int*   rank  = (int*)(ws + WS_RANK);
    int*   perm  = (int*)(ws + WS_PERM);
    int*   gsrc  = (int*)(ws + WS_GSRC);
    _Float16* weh = (_Float16*)(ws + WS_WEH);
    unsigned short* wph = (unsigned short*)(ws + WS_WPH);
    unsigned short* wpl = (unsigned short*)(ws + WS_WPL);
    float* wsT   = (float*)(ws + WS_WST);
    float* wnT   = (float*)(ws + WS_WNT);

    // zero deg every call (count accumulates via atomics)
    hipMemsetAsync(ws + WS_DEG, 0, 0x8000, stream);

    prep_count_kernel<<<768, 256, 0, stream>>>(W_edge, W_preagg, W_self, W_neigh,
                                               dst, weh, wph, wpl, wsT, wnT,
                                               deg, rank);
    preagg_scan_kernel<<<257, 256, 0, stream>>>(h_neigh, h_self, wph, wpl, deg,
                                                hn, hs, off);
    fill_kernel<<<NEDGES / 256, 256, 0, stream>>>(src, dst, off, rank, perm, gsrc);
    edge_kernel<<<2048, 256, 0, stream>>>(ef, weh, b_edge, hn, perm, gsrc, msg);
    final_kernel<<<NNODES / 4, 256, 0, stream>>>(hs, msg, deg, off, wsT, wnT, out);
}